// Round 1
// baseline (337.266 us; speedup 1.0000x reference)
//
#include <hip/hip_runtime.h>
#include <hip/hip_bf16.h>
#include <stdint.h>

#define NROWS      65536
#define RPB        32
#define NBLK       (NROWS/RPB)      // 2048
#define H2N        100
#define KPAD       128
#define N3         1224
#define NPAD       1232             // 77 tiles of 16
#define NTILES     77
#define NT_LDS     68               // n-tiles mirrored to LDS for the tail gather
#define TAILC      (NT_LDS*16)      // 1088 columns
#define OUTW       2193
#define NJ         57
#define TAILN      (NJ*17)          // 969

typedef __attribute__((ext_vector_type(8))) short bf16x8;
typedef __attribute__((ext_vector_type(4))) float f32x4;

__device__ __forceinline__ float fast_sigmoid(float z){
    return __builtin_amdgcn_rcpf(1.0f + __expf(-z));
}

__device__ __forceinline__ unsigned short f2bf(float v){
    __hip_bfloat16 h = __float2bfloat16(v);
    return *reinterpret_cast<unsigned short*>(&h);
}

// W3 (100 x 1224 f32, row-major) -> w3t[col][k] bf16, zero-padded to [1232][128]
__global__ void prep_w3t_kernel(const float* __restrict__ W3,
                                unsigned short* __restrict__ w3t){
    int idx = blockIdx.x * 256 + threadIdx.x;   // < NPAD*KPAD
    int c = idx >> 7;
    int k = idx & 127;
    float v = (k < H2N && c < N3) ? W3[k * N3 + c] : 0.0f;
    w3t[idx] = f2bf(v);
}

__global__ __launch_bounds__(256)
void snn_kernel(const float* __restrict__ x,
                const float* __restrict__ W1, const float* __restrict__ b1,
                const float* __restrict__ W2, const float* __restrict__ b2,
                const float* __restrict__ b3,
                const unsigned short* __restrict__ w3t,
                const float* __restrict__ wgt,
                const int* __restrict__ idx1, const int* __restrict__ idx2,
                float* __restrict__ out)
{
    __shared__ __align__(16) unsigned short lds_h2[RPB][KPAD];   // 8 KB, A-tiles (bf16, K zero-padded)
    __shared__ __align__(16) unsigned short lds_h3[RPB][TAILC];  // 68 KB, h3 mirror for tail
    __shared__ float lds_h1[RPB][10];
    __shared__ float lds_w[NJ];
    __shared__ int   lds_i1[NJ], lds_i2[NJ];

    const int t    = threadIdx.x;
    const int row0 = blockIdx.x * RPB;

    if (t < NJ){ lds_w[t] = wgt[t]; lds_i1[t] = idx1[t]; lds_i2[t] = idx2[t]; }

    // ---- layer 1 (fp32): h1[r][j], 32 rows x 10
    for (int i = t; i < RPB * 10; i += 256){
        int r = i / 10, j = i - r * 10;
        lds_h1[r][j] = fast_sigmoid(x[row0 + r] * W1[j] + b1[j]);
    }
    __syncthreads();

    // ---- layer 2 (fp32 -> bf16 LDS, zero-pad k=100..127)
    for (int i = t; i < RPB * KPAD; i += 256){
        int r = i & (RPB - 1), c = i >> 5;
        float v = 0.0f;
        if (c < H2N){
            float z = b2[c];
            #pragma unroll
            for (int j = 0; j < 10; ++j) z += lds_h1[r][j] * W2[j * H2N + c];
            v = fast_sigmoid(z);
        }
        lds_h2[r][c] = f2bf(v);
    }
    __syncthreads();

    // ---- layer 3 via MFMA 16x16x32 bf16, K = 128 (4 k-steps)
    const int lane = t & 63, wid = t >> 6;
    const int rt = wid >> 1, par = wid & 1;   // row-tile 0/1, n-parity 0/1
    const int lm = lane & 15, lg = lane >> 4;

    // A frags: lane holds A[row = rt*16+lm][k = ks*32 + lg*8 + e]
    bf16x8 afr[4];
    #pragma unroll
    for (int ks = 0; ks < 4; ++ks)
        afr[ks] = *reinterpret_cast<const bf16x8*>(&lds_h2[rt * 16 + lm][ks * 32 + lg * 8]);

    for (int nt = par; nt < NTILES; nt += 2){
        const int c0 = nt * 16 + lm;
        // B frags straight from L2-resident w3t[col][k] (contiguous 16B per lane)
        const unsigned short* bp = w3t + (size_t)c0 * KPAD + lg * 8;
        bf16x8 bfr[4];
        #pragma unroll
        for (int ks = 0; ks < 4; ++ks)
            bfr[ks] = *reinterpret_cast<const bf16x8*>(bp + ks * 32);

        f32x4 acc = {0.0f, 0.0f, 0.0f, 0.0f};
        #pragma unroll
        for (int ks = 0; ks < 4; ++ks)
            acc = __builtin_amdgcn_mfma_f32_16x16x32_bf16(afr[ks], bfr[ks], acc, 0, 0, 0);

        const bool  valid = (c0 < N3);
        const float b3v   = valid ? b3[c0] : 0.0f;
        const int   lrow  = rt * 16 + lg * 4;
        #pragma unroll
        for (int r = 0; r < 4; ++r){
            float h = fast_sigmoid(acc[r] + b3v);
            if (valid) out[(size_t)(row0 + lrow + r) * OUTW + c0] = h;   // D: row=lg*4+r, col=lm
            if (nt < NT_LDS) lds_h3[lrow + r][c0] = f2bf(h);
        }
    }
    __syncthreads();

    // ---- tail: out[:, 1224 + j*17 + k] = w[j]*h3[i1[j]*17+k] + (1-w[j])*h3[i2[j]*17+k]
    for (int r = 0; r < RPB; ++r){
        float* orow = out + (size_t)(row0 + r) * OUTW + N3;
        for (int p = t; p < TAILN; p += 256){
            int j = p / 17, k = p - j * 17;
            float wj = lds_w[j];
            int c1 = lds_i1[j] * 17 + k;
            int c2 = lds_i2[j] * 17 + k;
            float v1 = (c1 < TAILC) ? __uint_as_float(((unsigned)lds_h3[r][c1]) << 16)
                                    : out[(size_t)(row0 + r) * OUTW + c1];
            float v2 = (c2 < TAILC) ? __uint_as_float(((unsigned)lds_h3[r][c2]) << 16)
                                    : out[(size_t)(row0 + r) * OUTW + c2];
            orow[p] = wj * v1 + (1.0f - wj) * v2;
        }
    }
}

extern "C" void kernel_launch(void* const* d_in, const int* in_sizes, int n_in,
                              void* d_out, int out_size, void* d_ws, size_t ws_size,
                              hipStream_t stream)
{
    const float* x   = (const float*)d_in[0];
    const float* W1  = (const float*)d_in[1];
    const float* b1  = (const float*)d_in[2];
    const float* W2  = (const float*)d_in[3];
    const float* b2  = (const float*)d_in[4];
    const float* W3  = (const float*)d_in[5];
    const float* b3  = (const float*)d_in[6];
    const float* wgt = (const float*)d_in[7];
    const int*   i1  = (const int*)d_in[8];
    const int*   i2  = (const int*)d_in[9];
    float* out = (float*)d_out;
    unsigned short* w3t = (unsigned short*)d_ws;   // 1232*128*2 = 315,392 B

    prep_w3t_kernel<<<(NPAD * KPAD) / 256, 256, 0, stream>>>(W3, w3t);
    snn_kernel<<<NBLK, 256, 0, stream>>>(x, W1, b1, W2, b2, b3, w3t, wgt, i1, i2, out);
}